// Round 14
// baseline (8941.382 us; speedup 1.0000x reference)
//
#include <hip/hip_runtime.h>
#include <cstddef>

// Problem constants (from reference setup_inputs)
#define S_ 512
#define B_ 64
#define I_ 256
#define H_ 1024

#define NG 8     // batch groups (8 batches each)
#define GB 8     // batches per group
#define JT 16    // j rows per block
#define GBLK 64  // blocks per group (= 1024/JT)

// ---------------------------------------------------------------------------
// Transpose: out[c*R + r] = in[r*C + c].  R,C multiples of 32. (Wx only)
// ---------------------------------------------------------------------------
__global__ __launch_bounds__(256) void transpose_k(const float* __restrict__ in,
                                                   float* __restrict__ out,
                                                   int R, int C) {
  __shared__ float t[32][33];
  int c0 = blockIdx.x * 32, r0 = blockIdx.y * 32;
  int x = threadIdx.x & 31, y = threadIdx.x >> 5;
  for (int i = 0; i < 32; i += 8) {
    t[y + i][x] = in[(size_t)(r0 + y + i) * C + (c0 + x)];
  }
  __syncthreads();
  for (int i = 0; i < 32; i += 8) {
    out[(size_t)(c0 + y + i) * R + (r0 + x)] = t[x][y + i];
  }
}

// ---------------------------------------------------------------------------
// xproj: out[m*H + j] = dot(x[m, 0:256], WxT[:, j]) + bx[j]
// 8 m-rows per block.  grid = (H/256 = 4, S*B/8 = 4096)
// ---------------------------------------------------------------------------
__global__ __launch_bounds__(256) void xproj_kernel(const float* __restrict__ x,
                                                    const float* __restrict__ WxT,
                                                    const float* __restrict__ bx,
                                                    float* __restrict__ out) {
  __shared__ float xs[8][I_];
  int tid = threadIdx.x;
  int j = blockIdx.x * 256 + tid;
  size_t m0 = (size_t)blockIdx.y * 8;
  const float* xrow = x + m0 * I_;
  #pragma unroll
  for (int r = 0; r < 8; ++r) xs[r][tid] = xrow[(size_t)r * I_ + tid];
  __syncthreads();

  float bj = bx[j];
  float a[8];
  #pragma unroll
  for (int r = 0; r < 8; ++r) a[r] = bj;
  const float* wp = WxT + j;
  for (int k = 0; k < I_; k += 4) {
    float w0 = wp[(size_t)(k + 0) * H_];
    float w1 = wp[(size_t)(k + 1) * H_];
    float w2 = wp[(size_t)(k + 2) * H_];
    float w3 = wp[(size_t)(k + 3) * H_];
    #pragma unroll
    for (int r = 0; r < 8; ++r) {
      float4 v = *(const float4*)&xs[r][k];
      a[r] += w0 * v.x + w1 * v.y + w2 * v.z + w3 * v.w;
    }
  }
  #pragma unroll
  for (int r = 0; r < 8; ++r) out[(m0 + r) * H_ + j] = a[r];
}

// ---------------------------------------------------------------------------
// Persistent recurrence kernel, thread-per-(j,b), W streamed from L2.
//   512 blocks x 256 threads, 2 blocks/CU; block (g = blk>>6, jt = blk&63)
//   owns j rows [jt*16,+16) of batch-group g.  Colocated blocks (i, i+256)
//   serve different groups -> CU scheduler overlaps one group's barrier wait
//   with the other group's compute (replaces r12's serial A/B phases).
//   thread (b = tid&7, half = (tid>>3)&1, jj = tid>>4): computes the
//   half-dot (512 k) for output (j0+jj, b0+b); ONE shfl_xor(8) combines
//   halves (vs r12's 40-op reduce chain -> per-output cost was stuck at
//   ~72-76 cy across r5/r8/r12 because of it).
//   W[j0+jj] row is read by 8 b-lanes at the same address (broadcast
//   coalesced) -> ~128KB/CU/step from L2, hidden under the 2048-cy FMA floor.
//   h staged in LDS with b-XOR swizzle: phys f4 slot = b*256 + (kk ^ b);
//   reads hit all 8 bank-quads 2-way (free); affine per unroll slot.
//   Sync: per-group 64-flag array, sc1 stores + parallel poll (proven r8+).
// ---------------------------------------------------------------------------
__global__ __launch_bounds__(256, 2) void rnn_persistent(
    const float* __restrict__ Wh, const float* __restrict__ bh,
    float* __restrict__ out, unsigned* __restrict__ flags) {
  __shared__ float4 Hs4[GB * 256];  // 32 KB; logical (b,kk) at b*256 + (kk^b)

  const int tid = threadIdx.x;
  const int g  = blockIdx.x >> 6;  // batch-group (0..7)
  const int jt = blockIdx.x & 63;  // j-tile (0..63)
  const int j0 = jt * JT, b0 = g * GB;
  const int b    = tid & 7;         // batch within group
  const int half = (tid >> 3) & 1;  // k-half (512 floats each)
  const int jj   = tid >> 4;        // 0..15 : j row within tile

  const float bh_j = bh[j0 + jj];
  const size_t oidx = (size_t)(b0 + b) * H_ + (size_t)(j0 + jj);
  const float4* const wrow =
      (const float4*)(Wh + (size_t)(j0 + jj) * H_ + (size_t)half * 512);
  const int hbase = b * 256 + half * 128;  // f4 base in Hs4 (pre-XOR)
  float* const out_last = out + (size_t)S_ * B_ * H_;
  unsigned* const flagg = flags + (size_t)g * GBLK;

  for (int t = 0; t < S_; ++t) {
    float* orow = out + (size_t)t * B_ * H_;
    float xv = orow[oidx];  // xproj_t (private line, written pre-kernel)

    float s = 0.f;
    if (t > 0) {
      if (tid < GBLK) {  // parallel poll of the 64 producer flags
        unsigned* fp = &flagg[tid];
        while (__hip_atomic_load(fp, __ATOMIC_RELAXED,
                                 __HIP_MEMORY_SCOPE_AGENT) < (unsigned)t)
          __builtin_amdgcn_s_sleep(1);
      }
      __syncthreads();  // flags passed; all waves done with Hs4 of step t-1

      // ---- stage h_{t-1}: 8 batched dwordx4 sc1 loads, one drain ----
      const float* hsrc =
          (const float*)(out + (size_t)(t - 1) * B_ * H_ + (size_t)b0 * H_);
      float4 hv[8];
      #pragma unroll
      for (int q = 0; q < 8; ++q) {
        const float* ap = hsrc + (size_t)(q * 256 + tid) * 4;
        asm volatile("global_load_dwordx4 %0, %1, off sc1"
                     : "=v"(hv[q]) : "v"(ap));
      }
      asm volatile("s_waitcnt vmcnt(0)" ::: "memory");
      __builtin_amdgcn_sched_barrier(0);
      #pragma unroll
      for (int q = 0; q < 8; ++q) {
        // logical f4 index f = q*256 + tid  (b=q, kk=tid) -> phys q*256+(tid^q)
        Hs4[q * 256 + (tid ^ q)] = hv[q];
      }
      __syncthreads();

      // ---- half-dot: 128 f4 of W (L2 stream) x h (LDS broadcast) ----
      float4 accA = {0.f, 0.f, 0.f, 0.f};
      float4 accB = {0.f, 0.f, 0.f, 0.f};
      for (int k8 = 0; k8 < 128; k8 += 8) {
        #pragma unroll
        for (int i = 0; i < 8; ++i) {
          float4 w = wrow[k8 + i];
          float4 h = Hs4[hbase + k8 + (i ^ b)];
          // Pairing check (round-7 lesson): phys hbase+k8+(i^b) holds logical
          // kk = (half*128+k8+(i^b))^b = half*128+k8+i  (low 3 bits of base
          // are 0, XOR cancels once) -> pairs with wrow[k8+i].  w index == i.
          if (i & 1) {
            accB.x += w.x * h.x; accB.y += w.y * h.y;
            accB.z += w.z * h.z; accB.w += w.w * h.w;
          } else {
            accA.x += w.x * h.x; accA.y += w.y * h.y;
            accA.z += w.z * h.z; accA.w += w.w * h.w;
          }
        }
      }
      float sum = ((accA.x + accA.y) + (accA.z + accA.w)) +
                  ((accB.x + accB.y) + (accB.z + accB.w));
      s = sum + __shfl_xor(sum, 8, 64);  // combine the two k-halves
    }

    if (half == 0) {
      float hval = tanhf(s + bh_j + xv);
      if (t == S_ - 1) out_last[oidx] = hval;
      __hip_atomic_store(&orow[oidx], hval, __ATOMIC_RELAXED,
                         __HIP_MEMORY_SCOPE_AGENT);
    }

    if (t < S_ - 1) {
      asm volatile("s_waitcnt vmcnt(0)" ::: "memory");  // drain sc1 h stores
      __syncthreads();  // all waves drained (and done reading Hs4)
      if (tid == 0)
        __hip_atomic_store(&flagg[jt], (unsigned)(t + 1), __ATOMIC_RELAXED,
                           __HIP_MEMORY_SCOPE_AGENT);
      __syncthreads();
    }
  }
}

// ---------------------------------------------------------------------------
// Launch. ws layout: WxT (256*1024 f32 = 1MB) | flags (8 x 64 u32)
// Cooperative launch preferred; if refused (512 blocks), plain launch is
// safe: __launch_bounds__(256,2) -> <=128 VGPR -> 2 blocks/CU x 256 CUs =
// all 512 co-resident at dispatch (LDS would allow 5/CU; VGPR binds at 2).
// ---------------------------------------------------------------------------
extern "C" void kernel_launch(void* const* d_in, const int* in_sizes, int n_in,
                              void* d_out, int out_size, void* d_ws, size_t ws_size,
                              hipStream_t stream) {
  const float* x  = (const float*)d_in[0];
  const float* Wx = (const float*)d_in[1];
  const float* bx = (const float*)d_in[2];
  const float* Wh = (const float*)d_in[3];
  const float* bh = (const float*)d_in[4];
  float* out = (float*)d_out;
  float* WxT = (float*)d_ws;                            // [I_][H_]
  unsigned* flags = (unsigned*)(WxT + (size_t)I_ * H_); // 8 x 64

  (void)hipMemsetAsync(flags, 0, NG * GBLK * sizeof(unsigned), stream);
  hipLaunchKernelGGL(transpose_k, dim3(I_ / 32, H_ / 32), dim3(256), 0, stream,
                     Wx, WxT, H_, I_);
  hipLaunchKernelGGL(xproj_kernel, dim3(H_ / 256, (S_ * B_) / 8), dim3(256), 0, stream,
                     x, WxT, bx, out);

  void* args[] = {(void*)&Wh, (void*)&bh, (void*)&out, (void*)&flags};
  hipError_t e = hipLaunchCooperativeKernel((const void*)rnn_persistent,
                                            dim3(512), dim3(256), args, 0, stream);
  if (e != hipSuccess) {
    hipLaunchKernelGGL(rnn_persistent, dim3(512), dim3(256), 0, stream,
                       Wh, bh, out, flags);
  }
}